// Round 3
// baseline (422.839 us; speedup 1.0000x reference)
//
#include <hip/hip_runtime.h>
#include <math.h>

// B=4 graphs, N=256 nodes/graph (128+128), F=256, L=3 layers.
// Single persistent kernel: 256 blocks x 256 threads (co-resident), phases
// separated by a device-scope atomic grid barrier. All GEMMs are bf16 MFMA
// 16x16x32, one wave per 16x16 output tile, no LDS in K-loops.

typedef __attribute__((ext_vector_type(8))) short short8;   // 8 bf16
typedef __attribute__((ext_vector_type(4))) float f32x4;
typedef unsigned short u16;
typedef unsigned int   u32;

__device__ __forceinline__ u16 f2bf(float f) {
    union { float f; u32 u; } v; v.f = f;
    u32 r = v.u + 0x7fffu + ((v.u >> 16) & 1u);     // RNE
    return (u16)(r >> 16);
}
__device__ __forceinline__ short8 ld8(const u16* p) {
    return __builtin_bit_cast(short8, *(const int4*)p);
}

// Monotone-counter grid barrier; grid MUST be exactly 256 blocks.
__device__ __forceinline__ void gsync(u32* bar) {
    __syncthreads();
    if (threadIdx.x == 0) {
        u32 old = __hip_atomic_fetch_add(bar, 1u, __ATOMIC_ACQ_REL, __HIP_MEMORY_SCOPE_AGENT);
        u32 gen = (old >> 8) + 1;                   // /256
        while ((__hip_atomic_load(bar, __ATOMIC_ACQUIRE, __HIP_MEMORY_SCOPE_AGENT) >> 8) < gen)
            __builtin_amdgcn_s_sleep(1);
    }
    __syncthreads();
}

__global__ __launch_bounds__(256, 1) void k_fused(
    const float* __restrict__ desc0, const float* __restrict__ desc1,
    const float* __restrict__ conv_w, const float* __restrict__ conv_q,
    const float* __restrict__ conv_k, const float* __restrict__ conv_b,
    const float* __restrict__ lin_w,  const float* __restrict__ lin_b,
    const float* __restrict__ bn_w,   const float* __restrict__ bn_b,
    float* __restrict__ out,
    float* __restrict__ x,  u16* __restrict__ xb,
    u16* __restrict__ Wt,   u16* __restrict__ lwb, u16* __restrict__ Ht,
    float* __restrict__ qpart, float* __restrict__ kpart,
    u16* __restrict__ alphab, u16* __restrict__ msg1b,
    float* __restrict__ msg2, float* __restrict__ sums, float* __restrict__ sumsq,
    u32* bar)
{
    __shared__ __align__(16) float T[4][16 * 20];   // per-wave transpose slices
    const int tid = threadIdx.x, blk = blockIdx.x;
    const int w = blk * 4 + (tid >> 6);             // global wave id 0..1023
    const int lane = tid & 63;
    const int row = lane & 15, kg = lane >> 4, widx = tid >> 6;
    const int tg = blk * 256 + tid;                 // global thread id 0..65535

    // ---- P0: pack x (fp32 + bf16) and prep weights (Wt transposed, lwb) ----
    #pragma unroll
    for (int i = tg; i < 262144; i += 65536) {
        int node = i >> 8, f = i & 255, b = node >> 8, nl = node & 255;
        float v = (nl < 128) ? desc0[b * 32768 + f * 128 + nl]
                             : desc1[b * 32768 + f * 128 + (nl - 128)];
        x[i] = v; xb[i] = f2bf(v);
    }
    for (int i = tg; i < 786432; i += 65536) {
        if (i < 393216) {
            int mat = i >> 16, rem = i & 65535, e = rem >> 8, f = rem & 255;
            Wt[i] = f2bf(conv_w[mat * 65536 + f * 256 + e]);
        } else {
            int o2 = i - 393216;
            lwb[o2] = f2bf(lin_w[o2]);
        }
    }
    gsync(bar);

    for (int layer = 0; layer < 3; ++layer) {
        const u16* cwt = Wt + layer * 131072;
        const u16* lwp = lwb + layer * 131072;
        const float* cq = conv_q + layer * 256;
        const float* ck = conv_k + layer * 256;
        const float* cb = conv_b + layer * 256;
        const float* lb = lin_b + layer * 256;
        const float* bw = bn_w + layer * 256;
        const float* bb = bn_b + layer * 256;

        // ---- P1: Ht[r][e][node] = (xb @ Wt[r])^T, + qs/ks e-chunk partials --
        {
            const int mt = w >> 4, et = w & 15;
            const int m0 = mt * 16, e0 = et * 16;
            const u16* A  = xb + (m0 + row) * 256 + kg * 8;
            const u16* B0 = cwt + (e0 + row) * 256 + kg * 8;
            const u16* B1 = B0 + 65536;
            f32x4 acc0 = {0.f,0.f,0.f,0.f}, acc1 = {0.f,0.f,0.f,0.f};
            #pragma unroll
            for (int k0 = 0; k0 < 256; k0 += 32) {
                short8 a = ld8(A + k0);
                acc0 = __builtin_amdgcn_mfma_f32_16x16x32_bf16(a, ld8(B0 + k0), acc0, 0, 0, 0);
                acc1 = __builtin_amdgcn_mfma_f32_16x16x32_bf16(a, ld8(B1 + k0), acc1, 0, 0, 0);
            }
            // D: col(lane&15)=e, row(kg*4+c)=node -> write transposed Ht
            ushort4 o0, o1;
            o0.x = f2bf(acc0[0]); o0.y = f2bf(acc0[1]); o0.z = f2bf(acc0[2]); o0.w = f2bf(acc0[3]);
            o1.x = f2bf(acc1[0]); o1.y = f2bf(acc1[1]); o1.z = f2bf(acc1[2]); o1.w = f2bf(acc1[3]);
            *(ushort4*)(Ht + (e0 + row) * 1024 + m0 + kg * 4) = o0;
            *(ushort4*)(Ht + 262144 + (e0 + row) * 1024 + m0 + kg * 4) = o1;
            // qs/ks partials over this tile's 16 e's (fp32 acc)
            float qe = cq[e0 + row], ke = ck[e0 + row];
            float pq0[4], pk0[4], pq1[4], pk1[4];
            #pragma unroll
            for (int c = 0; c < 4; ++c) {
                pq0[c] = acc0[c] * qe; pk0[c] = acc0[c] * ke;
                pq1[c] = acc1[c] * qe; pk1[c] = acc1[c] * ke;
            }
            #pragma unroll
            for (int off = 1; off < 16; off <<= 1) {
                #pragma unroll
                for (int c = 0; c < 4; ++c) {
                    pq0[c] += __shfl_xor(pq0[c], off);
                    pk0[c] += __shfl_xor(pk0[c], off);
                    pq1[c] += __shfl_xor(pq1[c], off);
                    pk1[c] += __shfl_xor(pk1[c], off);
                }
            }
            if (row == 0) {
                float4 a4 = {pq0[0], pq0[1], pq0[2], pq0[3]};
                float4 b4 = {pk0[0], pk0[1], pk0[2], pk0[3]};
                float4 c4 = {pq1[0], pq1[1], pq1[2], pq1[3]};
                float4 d4 = {pk1[0], pk1[1], pk1[2], pk1[3]};
                *(float4*)&qpart[et * 1024 + m0 + kg * 4] = a4;
                *(float4*)&kpart[et * 1024 + m0 + kg * 4] = b4;
                *(float4*)&qpart[(16 + et) * 1024 + m0 + kg * 4] = c4;
                *(float4*)&kpart[(16 + et) * 1024 + m0 + kg * 4] = d4;
            }
        }
        gsync(bar);

        // ---- P2: alpha rows (leaky-relu + softmax), bf16 ---------------------
        {
            const int rowg = w;
            const int g = rowg >> 8, dl = rowg & 255, a = (rowg >> 7) & 1;
            const int s0 = lane * 4;
            const int t = ((s0 >> 7) == a) ? 0 : 1;   // 4 srcs never cross 128 split
            float qv = 0.f, kx = 0.f, ky = 0.f, kz = 0.f, kw = 0.f;
            #pragma unroll
            for (int c = 0; c < 16; ++c) {
                qv += qpart[(t * 16 + c) * 1024 + rowg];
                float4 k4 = *(const float4*)&kpart[(t * 16 + c) * 1024 + g * 256 + s0];
                kx += k4.x; ky += k4.y; kz += k4.z; kw += k4.w;
            }
            float l[4] = {qv + kx, qv + ky, qv + kz, qv + kw};
            float mx = -1e30f;
            #pragma unroll
            for (int j = 0; j < 4; ++j) {
                l[j] = (l[j] >= 0.f) ? l[j] : 0.2f * l[j];
                if (s0 + j == dl) l[j] = -1e30f;
                mx = fmaxf(mx, l[j]);
            }
            #pragma unroll
            for (int off = 32; off; off >>= 1) mx = fmaxf(mx, __shfl_xor(mx, off));
            float e[4]; float s = 0.f;
            #pragma unroll
            for (int j = 0; j < 4; ++j) { e[j] = __expf(l[j] - mx); s += e[j]; }
            #pragma unroll
            for (int off = 32; off; off >>= 1) s += __shfl_xor(s, off);
            float inv = 1.f / (s + 1e-16f);
            ushort4 o;
            o.x = f2bf(e[0] * inv); o.y = f2bf(e[1] * inv);
            o.z = f2bf(e[2] * inv); o.w = f2bf(e[3] * inv);
            *(ushort4*)(alphab + rowg * 256 + s0) = o;
        }
        gsync(bar);

        // ---- P3: msg1b = relu(alpha @ H_sel + cb), bf16 ----------------------
        {
            const int mt = w >> 4, et = w & 15;
            const int m0 = mt * 16, e0 = et * 16;
            const int g = m0 >> 8, a = (m0 >> 7) & 1;
            const u16* A = alphab + (m0 + row) * 256 + kg * 8;
            f32x4 acc = {0.f,0.f,0.f,0.f};
            #pragma unroll
            for (int k0 = 0; k0 < 256; k0 += 32) {
                const int t = (((k0 >> 7) & 1) == a) ? 0 : 1;   // tile-uniform rel
                const u16* B = Ht + t * 262144 + (e0 + row) * 1024 + g * 256 + k0 + kg * 8;
                acc = __builtin_amdgcn_mfma_f32_16x16x32_bf16(ld8(A + k0), ld8(B), acc, 0, 0, 0);
            }
            float bias = cb[e0 + row];
            float* Tw = &T[widx][0];
            #pragma unroll
            for (int c = 0; c < 4; ++c)
                Tw[(kg * 4 + c) * 20 + row] = fmaxf(acc[c] + bias, 0.f);
            __syncthreads();
            float4 v = *(float4*)&Tw[row * 20 + kg * 4];
            u32 lo = (u32)f2bf(v.x) | ((u32)f2bf(v.y) << 16);
            u32 hi = (u32)f2bf(v.z) | ((u32)f2bf(v.w) << 16);
            uint2 ov = {lo, hi};
            *(uint2*)(msg1b + (m0 + row) * 256 + e0 + kg * 4) = ov;
        }
        gsync(bar);

        // ---- P4: msg2 = concat(xb,msg1b) @ lwb^T + lb, + BN partials ---------
        {
            const int mt = w >> 4, nt = w & 15;
            const int m0 = mt * 16, n0 = nt * 16;
            const u16* A0 = xb    + (m0 + row) * 256 + kg * 8;
            const u16* A1 = msg1b + (m0 + row) * 256 + kg * 8;
            const u16* B  = lwp + (n0 + row) * 512 + kg * 8;
            f32x4 acc = {0.f,0.f,0.f,0.f};
            #pragma unroll
            for (int k0 = 0; k0 < 512; k0 += 32) {
                short8 av = (k0 < 256) ? ld8(A0 + k0) : ld8(A1 + (k0 - 256));
                acc = __builtin_amdgcn_mfma_f32_16x16x32_bf16(av, ld8(B + k0), acc, 0, 0, 0);
            }
            float bias = lb[n0 + row];
            float v0 = acc[0] + bias, v1 = acc[1] + bias, v2 = acc[2] + bias, v3 = acc[3] + bias;
            float s1 = v0 + v1 + v2 + v3;
            float s2 = v0 * v0 + v1 * v1 + v2 * v2 + v3 * v3;
            s1 += __shfl_xor(s1, 16); s1 += __shfl_xor(s1, 32);
            s2 += __shfl_xor(s2, 16); s2 += __shfl_xor(s2, 32);
            if (lane < 16) {
                sums [mt * 256 + n0 + lane] = s1;
                sumsq[mt * 256 + n0 + lane] = s2;
            }
            float* Tw = &T[widx][0];
            Tw[(kg * 4 + 0) * 20 + row] = v0;
            Tw[(kg * 4 + 1) * 20 + row] = v1;
            Tw[(kg * 4 + 2) * 20 + row] = v2;
            Tw[(kg * 4 + 3) * 20 + row] = v3;
            __syncthreads();
            float4 vv = *(float4*)&Tw[row * 20 + kg * 4];
            *(float4*)(msg2 + (m0 + row) * 256 + n0 + kg * 4) = vv;
        }
        gsync(bar);

        // ---- P5: BN apply + residual; refresh x (fp32) and xb (bf16) ---------
        {
            const int t = tid;
            float s1 = 0.f, s2 = 0.f;
            #pragma unroll 8
            for (int s = 0; s < 64; ++s) { s1 += sums[s * 256 + t]; s2 += sumsq[s * 256 + t]; }
            float mu  = s1 * (1.f / 1024.f);
            float var = s2 * (1.f / 1024.f) - mu * mu;     // biased, as reference
            float scale = bw[t] * rsqrtf(var + 1e-5f);
            float shift = bb[t] - mu * scale;
            #pragma unroll
            for (int j = 0; j < 4; ++j) {
                int idx = (blk * 4 + j) * 256 + t;
                float nv = x[idx] + msg2[idx] * scale + shift;
                x[idx] = nv; xb[idx] = f2bf(nv);
            }
        }
        gsync(bar);
    }

    // ---- P6: unpack to [B,F,N0] + [B,F,N1] ---------------------------------
    #pragma unroll
    for (int i = tg; i < 262144; i += 65536) {
        int half = (i >= 131072) ? 1 : 0;
        int j = i - half * 131072;
        int b = j >> 15, rem = j & 32767, f = rem >> 7, n = rem & 127;
        out[i] = x[(b * 256 + half * 128 + n) * 256 + f];
    }
}

// ----------------------------------------------------------------------------
extern "C" void kernel_launch(void* const* d_in, const int* in_sizes, int n_in,
                              void* d_out, int out_size, void* d_ws, size_t ws_size,
                              hipStream_t stream) {
    const float* desc0  = (const float*)d_in[0];
    const float* desc1  = (const float*)d_in[1];
    const float* conv_w = (const float*)d_in[2];
    const float* conv_q = (const float*)d_in[3];
    const float* conv_k = (const float*)d_in[4];
    const float* conv_b = (const float*)d_in[5];
    const float* lin_w  = (const float*)d_in[6];
    const float* lin_b  = (const float*)d_in[7];
    const float* bn_w   = (const float*)d_in[8];
    const float* bn_b   = (const float*)d_in[9];
    float* out = (float*)d_out;

    char* p = (char*)d_ws;
    float* x      = (float*)p; p += 1048576;
    u16*   xb     = (u16*)p;   p += 524288;
    u16*   Wt     = (u16*)p;   p += 786432;
    u16*   lwb    = (u16*)p;   p += 786432;
    u16*   Ht     = (u16*)p;   p += 1048576;
    float* qpart  = (float*)p; p += 131072;   // [32][1024]
    float* kpart  = (float*)p; p += 131072;
    u16*   alphab = (u16*)p;   p += 524288;
    u16*   msg1b  = (u16*)p;   p += 524288;
    float* msg2   = (float*)p; p += 1048576;
    float* sums   = (float*)p; p += 65536;    // [64][256]
    float* sumsq  = (float*)p; p += 65536;
    u32*   bar    = (u32*)p;   p += 256;

    hipMemsetAsync(bar, 0, 4, stream);        // barrier counter must start at 0

    k_fused<<<256, 256, 0, stream>>>(desc0, desc1, conv_w, conv_q, conv_k, conv_b,
                                     lin_w, lin_b, bn_w, bn_b, out,
                                     x, xb, Wt, lwb, Ht, qpart, kpart,
                                     alphab, msg1b, msg2, sums, sumsq, bar);
}

// Round 5
// 156.870 us; speedup vs baseline: 2.6955x; 2.6955x over previous
//
#include <hip/hip_runtime.h>
#include <math.h>

// B=4 graphs, N=256 nodes/graph (128+128), F=256, L=3 layers.
// 11 launches total: prep + 3x{hqk, attn, lin} + fin. No grid barriers
// (kernel boundaries provide cross-XCD coherence cheaply). GEMMs: bf16 MFMA
// 16x16x32, one wave per 16x16 tile, operands L2-resident.
//
// x-buffer chain (layer i reads xs[i], writes xs[i+1] iff do_bn):
//   layer0: reads x0, do_bn=0 (no write)  -> x state remains x0
//   layer1: reads x0, applies BN(layer0), writes x1
//   layer2: reads x1, applies BN(layer1), writes x0
//   fin   : reads x0, applies BN(layer2) into out
// Round-4 bug was xs={x0,x1,x0,x0} (layer1 read never-written x1).

typedef __attribute__((ext_vector_type(8))) short short8;   // 8 bf16
typedef __attribute__((ext_vector_type(4))) float f32x4;
typedef unsigned short u16;
typedef unsigned int   u32;

__device__ __forceinline__ u16 f2bf(float f) {
    union { float f; u32 u; } v; v.f = f;
    u32 r = v.u + 0x7fffu + ((v.u >> 16) & 1u);     // RNE
    return (u16)(r >> 16);
}
__device__ __forceinline__ short8 ld8(const u16* p) {
    return __builtin_bit_cast(short8, *(const int4*)p);
}

// ---- P0: pack x (fp32+bf16) + transpose conv_w -> Wt + cast lin_w -> lwb ---
__global__ __launch_bounds__(256) void k_prep(
    const float* __restrict__ d0, const float* __restrict__ d1,
    const float* __restrict__ conv_w, const float* __restrict__ lin_w,
    float* __restrict__ x, u16* __restrict__ xb,
    u16* __restrict__ Wt, u16* __restrict__ lwb) {
    for (int i = blockIdx.x * 256 + threadIdx.x; i < 1048576; i += 262144) {
        if (i < 262144) {
            int node = i >> 8, f = i & 255, b = node >> 8, nl = node & 255;
            float v = (nl < 128) ? d0[b * 32768 + f * 128 + nl]
                                 : d1[b * 32768 + f * 128 + (nl - 128)];
            x[i] = v; xb[i] = f2bf(v);
        } else if (i < 655360) {
            int o = i - 262144;                     // 6 mats of 256x256
            int mat = o >> 16, rem = o & 65535, e = rem >> 8, f = rem & 255;
            Wt[o] = f2bf(conv_w[mat * 65536 + f * 256 + e]);
        } else {
            int o = i - 655360;
            lwb[o] = f2bf(lin_w[o]);
        }
    }
}

// ---- K_A: BN-apply(prev) + H-GEMM + qs/ks partials --------------------------
// grid 256 = (64 m-tiles) x (4 e-groups); 256 thr (4 waves).
__global__ __launch_bounds__(256, 1) void k_hqk(
    const float* __restrict__ xprev, const float* __restrict__ msg2,
    const float* __restrict__ sums, const float* __restrict__ sumsq,
    const float* __restrict__ bw, const float* __restrict__ bb,
    const u16* __restrict__ cwt,                 // [2][256 e][256 f]
    const float* __restrict__ cq, const float* __restrict__ ck,
    float* __restrict__ xcur, u16* __restrict__ xb, u16* __restrict__ Ht,
    float* __restrict__ qpart, float* __restrict__ kpart, int do_bn) {
    __shared__ __align__(16) u16 Asub[16 * 264];  // [16 nodes][256 f] bf16, pad
    const int tid = threadIdx.x;
    const int mt = blockIdx.x >> 2, eg = blockIdx.x & 3;
    const int m0 = mt * 16;
    const int lane = tid & 63, widx = tid >> 6;
    const int row = lane & 15, kg = lane >> 4;

    float scale = 0.f, shift = 0.f;
    if (do_bn) {                                  // col = tid, redundant/block
        float s1 = 0.f, s2 = 0.f;
        #pragma unroll 8
        for (int c = 0; c < 64; ++c) { s1 += sums[c * 256 + tid]; s2 += sumsq[c * 256 + tid]; }
        float mu  = s1 * (1.f / 1024.f);
        float var = s2 * (1.f / 1024.f) - mu * mu;        // biased, as reference
        scale = bw[tid] * rsqrtf(var + 1e-5f);
        shift = bb[tid] - mu * scale;
    }
    #pragma unroll
    for (int r = 0; r < 16; ++r) {                // x_cur rows, col = tid
        int idx = (m0 + r) * 256 + tid;
        float v = xprev[idx];
        if (do_bn) v += msg2[idx] * scale + shift;
        u16 hb = f2bf(v);
        Asub[r * 264 + tid] = hb;
        if (do_bn && eg == 0) { xcur[idx] = v; xb[idx] = hb; }
    }
    __syncthreads();

    const int et = eg * 4 + widx, e0 = et * 16;   // e-tile 0..15
    const u16* B0 = cwt + (e0 + row) * 256 + kg * 8;
    const u16* B1 = B0 + 65536;
    const u16* Ap = &Asub[row * 264 + kg * 8];
    f32x4 acc0 = {0.f,0.f,0.f,0.f}, acc1 = {0.f,0.f,0.f,0.f};
    #pragma unroll
    for (int k0 = 0; k0 < 256; k0 += 32) {
        short8 a = ld8(Ap + k0);
        acc0 = __builtin_amdgcn_mfma_f32_16x16x32_bf16(a, ld8(B0 + k0), acc0, 0, 0, 0);
        acc1 = __builtin_amdgcn_mfma_f32_16x16x32_bf16(a, ld8(B1 + k0), acc1, 0, 0, 0);
    }
    // D: col(lane&15)=e, row(kg*4+c)=node -> store transposed Ht[r][e][node]
    ushort4 o0, o1;
    o0.x = f2bf(acc0[0]); o0.y = f2bf(acc0[1]); o0.z = f2bf(acc0[2]); o0.w = f2bf(acc0[3]);
    o1.x = f2bf(acc1[0]); o1.y = f2bf(acc1[1]); o1.z = f2bf(acc1[2]); o1.w = f2bf(acc1[3]);
    *(ushort4*)(Ht + (e0 + row) * 1024 + m0 + kg * 4) = o0;
    *(ushort4*)(Ht + 262144 + (e0 + row) * 1024 + m0 + kg * 4) = o1;
    // qs/ks partials over this tile's 16 e's
    float qe = cq[e0 + row], ke = ck[e0 + row];
    float pq0[4], pk0[4], pq1[4], pk1[4];
    #pragma unroll
    for (int c = 0; c < 4; ++c) {
        pq0[c] = acc0[c] * qe; pk0[c] = acc0[c] * ke;
        pq1[c] = acc1[c] * qe; pk1[c] = acc1[c] * ke;
    }
    #pragma unroll
    for (int off = 1; off < 16; off <<= 1) {
        #pragma unroll
        for (int c = 0; c < 4; ++c) {
            pq0[c] += __shfl_xor(pq0[c], off);
            pk0[c] += __shfl_xor(pk0[c], off);
            pq1[c] += __shfl_xor(pq1[c], off);
            pk1[c] += __shfl_xor(pk1[c], off);
        }
    }
    if (row == 0) {
        float4 a4 = {pq0[0], pq0[1], pq0[2], pq0[3]};
        float4 b4 = {pk0[0], pk0[1], pk0[2], pk0[3]};
        float4 c4 = {pq1[0], pq1[1], pq1[2], pq1[3]};
        float4 d4 = {pk1[0], pk1[1], pk1[2], pk1[3]};
        *(float4*)&qpart[et * 1024 + m0 + kg * 4] = a4;
        *(float4*)&kpart[et * 1024 + m0 + kg * 4] = b4;
        *(float4*)&qpart[(16 + et) * 1024 + m0 + kg * 4] = c4;
        *(float4*)&kpart[(16 + et) * 1024 + m0 + kg * 4] = d4;
    }
}

// ---- K_B: alpha (in-LDS) + attn GEMM + relu/bias ---------------------------
// grid 256 = (64 dst-tiles) x (4 e-groups); 256 thr.
__global__ __launch_bounds__(256, 1) void k_attn(
    const float* __restrict__ qpart, const float* __restrict__ kpart,
    const u16* __restrict__ Ht, const float* __restrict__ cb,
    u16* __restrict__ msg1b) {
    __shared__ __align__(16) u16 Atile[16 * 264]; // alpha bf16 [16 dst][256 src]
    __shared__ float ksl[2][256];
    __shared__ float qsl[2][16];
    __shared__ __align__(16) float T[4][16 * 20];
    const int tid = threadIdx.x;
    const int mt = blockIdx.x >> 2, eg = blockIdx.x & 3;
    const int m0 = mt * 16;
    const int g = m0 >> 8, a = (m0 >> 7) & 1;
    {   // ks for both relations, this graph's 256 srcs
        float k0s = 0.f, k1s = 0.f;
        #pragma unroll
        for (int c = 0; c < 16; ++c) {
            k0s += kpart[c * 1024 + g * 256 + tid];
            k1s += kpart[(16 + c) * 1024 + g * 256 + tid];
        }
        ksl[0][tid] = k0s; ksl[1][tid] = k1s;
    }
    if (tid < 32) {
        int rel = tid >> 4, r = tid & 15;
        float q = 0.f;
        #pragma unroll
        for (int c = 0; c < 16; ++c) q += qpart[(rel * 16 + c) * 1024 + m0 + r];
        qsl[rel][r] = q;
    }
    __syncthreads();
    {   // logits+softmax: thread = (dst r = tid>>4, src chunk j = tid&15)
        const int r = tid >> 4, j = tid & 15;
        const int dl = (m0 + r) & 255;
        const int s0 = j * 16;
        const int rel = ((s0 >> 7) == a) ? 0 : 1; // chunk never crosses 128
        float qv = qsl[rel][r];
        float l[16], mx = -1e30f;
        #pragma unroll
        for (int i2 = 0; i2 < 16; ++i2) {
            float v = qv + ksl[rel][s0 + i2];
            v = (v >= 0.f) ? v : 0.2f * v;        // leaky_relu 0.2
            if (s0 + i2 == dl) v = -1e30f;        // no self-loop
            l[i2] = v; mx = fmaxf(mx, v);
        }
        #pragma unroll
        for (int off = 1; off < 16; off <<= 1) mx = fmaxf(mx, __shfl_xor(mx, off));
        float s = 0.f;
        #pragma unroll
        for (int i2 = 0; i2 < 16; ++i2) { l[i2] = __expf(l[i2] - mx); s += l[i2]; }
        #pragma unroll
        for (int off = 1; off < 16; off <<= 1) s += __shfl_xor(s, off);
        float inv = 1.f / (s + 1e-16f);
        #pragma unroll
        for (int i2 = 0; i2 < 16; i2 += 2) {
            u32 p = (u32)f2bf(l[i2] * inv) | ((u32)f2bf(l[i2 + 1] * inv) << 16);
            *(u32*)&Atile[r * 264 + s0 + i2] = p;
        }
    }
    __syncthreads();
    const int lane = tid & 63, widx = tid >> 6;
    const int row = lane & 15, kg = lane >> 4;
    const int et = eg * 4 + widx, e0 = et * 16;
    const u16* Ap = &Atile[row * 264 + kg * 8];
    f32x4 acc = {0.f,0.f,0.f,0.f};
    #pragma unroll
    for (int k0 = 0; k0 < 256; k0 += 32) {
        const int rel = (((k0 >> 7) & 1) == a) ? 0 : 1;   // tile-uniform
        const u16* B = Ht + rel * 262144 + (e0 + row) * 1024 + g * 256 + k0 + kg * 8;
        acc = __builtin_amdgcn_mfma_f32_16x16x32_bf16(ld8(Ap + k0), ld8(B), acc, 0, 0, 0);
    }
    float bias = cb[e0 + row];
    float* Tw = &T[widx][0];
    #pragma unroll
    for (int c = 0; c < 4; ++c)
        Tw[(kg * 4 + c) * 20 + row] = fmaxf(acc[c] + bias, 0.f);
    __syncthreads();
    float4 v = *(float4*)&Tw[row * 20 + kg * 4];
    u32 lo = (u32)f2bf(v.x) | ((u32)f2bf(v.y) << 16);
    u32 hi = (u32)f2bf(v.z) | ((u32)f2bf(v.w) << 16);
    uint2 ov = {lo, hi};
    *(uint2*)(msg1b + (m0 + row) * 256 + e0 + kg * 4) = ov;
}

// ---- K_C: lin GEMM (K=512) + BN partial stats ------------------------------
// grid 256 = (64 m-tiles) x (4 n-groups); 256 thr.
__global__ __launch_bounds__(256, 1) void k_lin(
    const u16* __restrict__ xb, const u16* __restrict__ msg1b,
    const u16* __restrict__ lwp, const float* __restrict__ lb,
    float* __restrict__ msg2, float* __restrict__ sums, float* __restrict__ sumsq) {
    __shared__ __align__(16) float T[4][16 * 20];
    const int tid = threadIdx.x, lane = tid & 63, widx = tid >> 6;
    const int row = lane & 15, kg = lane >> 4;
    const int mt = blockIdx.x >> 2, ng = blockIdx.x & 3;
    const int m0 = mt * 16;
    const int nt = ng * 4 + widx, n0 = nt * 16;
    const u16* A0 = xb    + (m0 + row) * 256 + kg * 8;
    const u16* A1 = msg1b + (m0 + row) * 256 + kg * 8;
    const u16* B  = lwp + (n0 + row) * 512 + kg * 8;
    f32x4 acc = {0.f,0.f,0.f,0.f};
    #pragma unroll
    for (int k0 = 0; k0 < 512; k0 += 32) {
        short8 av = (k0 < 256) ? ld8(A0 + k0) : ld8(A1 + (k0 - 256));
        acc = __builtin_amdgcn_mfma_f32_16x16x32_bf16(av, ld8(B + k0), acc, 0, 0, 0);
    }
    float bias = lb[n0 + row];
    float v0 = acc[0] + bias, v1 = acc[1] + bias, v2 = acc[2] + bias, v3 = acc[3] + bias;
    float s1 = v0 + v1 + v2 + v3;
    float s2 = v0 * v0 + v1 * v1 + v2 * v2 + v3 * v3;
    s1 += __shfl_xor(s1, 16); s1 += __shfl_xor(s1, 32);
    s2 += __shfl_xor(s2, 16); s2 += __shfl_xor(s2, 32);
    if (lane < 16) {
        sums [mt * 256 + n0 + lane] = s1;
        sumsq[mt * 256 + n0 + lane] = s2;
    }
    float* Tw = &T[widx][0];
    Tw[(kg * 4 + 0) * 20 + row] = v0;
    Tw[(kg * 4 + 1) * 20 + row] = v1;
    Tw[(kg * 4 + 2) * 20 + row] = v2;
    Tw[(kg * 4 + 3) * 20 + row] = v3;
    __syncthreads();
    float4 vv = *(float4*)&Tw[row * 20 + kg * 4];
    *(float4*)(msg2 + (m0 + row) * 256 + n0 + kg * 4) = vv;
}

// ---- K_fin: final BN + residual + unpack to [B,F,N0]|[B,F,N1] --------------
__global__ __launch_bounds__(256) void k_fin(
    const float* __restrict__ x2, const float* __restrict__ msg2,
    const float* __restrict__ sums, const float* __restrict__ sumsq,
    const float* __restrict__ bw, const float* __restrict__ bb,
    float* __restrict__ out) {
    const int blk = blockIdx.x, t = threadIdx.x;
    float s1 = 0.f, s2 = 0.f;
    #pragma unroll 8
    for (int c = 0; c < 64; ++c) { s1 += sums[c * 256 + t]; s2 += sumsq[c * 256 + t]; }
    float mu  = s1 * (1.f / 1024.f);
    float var = s2 * (1.f / 1024.f) - mu * mu;
    float scale = bw[t] * rsqrtf(var + 1e-5f);
    float shift = bb[t] - mu * scale;
    #pragma unroll
    for (int j = 0; j < 4; ++j) {
        int node = blk * 4 + j;
        int idx = node * 256 + t;
        float v = x2[idx] + msg2[idx] * scale + shift;
        int b = node >> 8, nl = node & 255, half = nl >> 7, n = nl & 127;
        out[half * 131072 + b * 32768 + t * 128 + n] = v;
    }
}

// ----------------------------------------------------------------------------
extern "C" void kernel_launch(void* const* d_in, const int* in_sizes, int n_in,
                              void* d_out, int out_size, void* d_ws, size_t ws_size,
                              hipStream_t stream) {
    const float* desc0  = (const float*)d_in[0];
    const float* desc1  = (const float*)d_in[1];
    const float* conv_w = (const float*)d_in[2];
    const float* conv_q = (const float*)d_in[3];
    const float* conv_k = (const float*)d_in[4];
    const float* conv_b = (const float*)d_in[5];
    const float* lin_w  = (const float*)d_in[6];
    const float* lin_b  = (const float*)d_in[7];
    const float* bn_w   = (const float*)d_in[8];
    const float* bn_b   = (const float*)d_in[9];
    float* out = (float*)d_out;

    char* p = (char*)d_ws;
    float* x0     = (float*)p; p += 1048576;
    float* x1     = (float*)p; p += 1048576;
    u16*   xb     = (u16*)p;   p += 524288;
    u16*   Wt     = (u16*)p;   p += 786432;    // [3][2][256e][256f]
    u16*   lwb    = (u16*)p;   p += 786432;
    u16*   Ht     = (u16*)p;   p += 1048576;   // [2][256e][1024node]
    float* qpart  = (float*)p; p += 131072;    // [32][1024]
    float* kpart  = (float*)p; p += 131072;
    u16*   msg1b  = (u16*)p;   p += 524288;
    float* msg2   = (float*)p; p += 1048576;
    float* sums   = (float*)p; p += 65536;     // [64][256]
    float* sumsq  = (float*)p; p += 65536;

    k_prep<<<1024, 256, 0, stream>>>(desc0, desc1, conv_w, lin_w, x0, xb, Wt, lwb);

    // layer i reads xs[i]; writes xs[i+1] only when do_bn (i>0). Layer 0
    // leaves x unchanged, so layer 1 must read x0 again.
    float* xs[4] = {x0, x0, x1, x0};
    for (int i = 0; i < 3; ++i) {
        const u16*   cwt = Wt + i * 131072;
        const u16*   lwp = lwb + i * 131072;
        const float* cq = conv_q + i * 256;
        const float* ck = conv_k + i * 256;
        const float* cb = conv_b + i * 256;
        const float* lb = lin_b + i * 256;
        const float* bwp = bn_w + (i ? (i - 1) * 256 : 0);   // prev-layer BN
        const float* bbp = bn_b + (i ? (i - 1) * 256 : 0);

        k_hqk<<<256, 256, 0, stream>>>(xs[i], msg2, sums, sumsq, bwp, bbp,
                                       cwt, cq, ck, xs[i + 1], xb, Ht,
                                       qpart, kpart, i > 0 ? 1 : 0);
        k_attn<<<256, 256, 0, stream>>>(qpart, kpart, Ht, cb, msg1b);
        k_lin<<<256, 256, 0, stream>>>(xb, msg1b, lwp, lb, msg2, sums, sumsq);
    }

    k_fin<<<256, 256, 0, stream>>>(xs[3], msg2, sums, sumsq,
                                   bn_w + 512, bn_b + 512, out);
}